// Round 11
// baseline (44.684 us; speedup 1.0000x reference)
//
#include <hip/hip_runtime.h>
#include <cstddef>

// RoIPool: features (B=2, C=256, H=50, W=50) f32, rois (R,4) f32, roi_indices (R,) int
// out (R, C, 7, 7) f32.
// Reference quirk preserved: h-bins from x coords (ri[:,0], ri[:,2]), w-bins from y.
//
// R3-winning split structure (every deviation regressed): kernel 1 transposes
// to (CSPLIT=4, B, H, W, 64) channel-last; kernel 2 = pool, grid (4, R),
// 448 thr = 7 waves (wave = ph, lane = channel), 28 waves/CU.
// Pool now uses separable column-max: stage colmax[w] = max over the h-bin's
// <=4 rows (branch-specialized, loads only real rows, 20 independent chains)
// into a per-wave LDS row, then each pw-bin = <=4 LDS reads + fmax. Each lane
// reads only its own writes -> NO barrier. LDS stride 64 -> conflict-free.
// Direct nontemporal stores (block covers a contiguous 12.25 KB out chunk).

namespace {
constexpr int OUTP = 7;
constexpr int BB = 2;
constexpr int CC = 256;
constexpr int HH = 50;
constexpr int WW = 50;
constexpr int HWSZ = HH * WW;
constexpr int CSPLIT = 4;
constexpr int CPS = CC / CSPLIT;   // 64 channels per slice
constexpr int ROWS = WW * CPS;     // featT row stride in floats
constexpr int LMAX = 19;           // max Lh/Lw on fast path
constexpr int WSTG = 20;           // staged colmax slots per wave
constexpr float NEGV = -3e38f;
}  // namespace

// (B, C, H*W) -> (CSPLIT, B, H*W, CPS) tiled transpose via LDS (R3-proven).
__global__ __launch_bounds__(256) void transpose_k(const float* __restrict__ in,
                                                   float* __restrict__ out) {
    __shared__ float tile[32][33];
    const int b = blockIdx.z;
    const int hw0 = blockIdx.x * 32;
    const int c0 = blockIdx.y * 32;
    const int tx = threadIdx.x;
#pragma unroll
    for (int i = threadIdx.y; i < 32; i += 8) {
        const int hw = hw0 + tx;
        float v = 0.0f;
        if (hw < HWSZ) v = in[(size_t)(b * CC + c0 + i) * HWSZ + hw];
        tile[i][tx] = v;
    }
    __syncthreads();
    const int ch = c0 + tx;
    const int s = ch >> 6;
    const int cin = ch & (CPS - 1);
#pragma unroll
    for (int i = threadIdx.y; i < 32; i += 8) {
        const int hw = hw0 + i;
        if (hw < HWSZ)
            out[((size_t)((s * BB + b) * HWSZ) + hw) * CPS + cin] = tile[tx][i];
    }
}

// Stage colmax for NH rows: 20 independent load chains (scalar w<Lw branches).
template <int NH>
__device__ inline void stage_colmax(const float* __restrict__ base, int Lw,
                                    float* __restrict__ cm) {
#pragma unroll
    for (int w = 0; w < WSTG; ++w) {
        if (w < Lw) {  // wave-uniform scalar branch
            const float* p = base + w * CPS;
            float m = p[0];
            if (NH > 1) m = fmaxf(m, p[ROWS]);
            if (NH > 2) m = fmaxf(m, p[2 * ROWS]);
            if (NH > 3) m = fmaxf(m, p[3 * ROWS]);
            cm[w * CPS] = m;
        }
    }
}

// Pool: grid (CSPLIT, R), 448 thr; wave = ph, lane = channel. Barrier-free.
__global__ __launch_bounds__(448) void roipool_cm(const float* __restrict__ featT,
                                                  const float* __restrict__ rois,
                                                  const int* __restrict__ ridx,
                                                  float* __restrict__ out) {
    __shared__ float colm[OUTP * WSTG * CPS];  // 35840 B; [ph][w][c]

    const int s = blockIdx.x;
    const int r = blockIdx.y;
    const int tid = threadIdx.x;
    const int c = tid & 63;
    const int ph = __builtin_amdgcn_readfirstlane(tid >> 6);  // 0..6

    const float4 rv = reinterpret_cast<const float4*>(rois)[r];
    int x1 = (int)(rv.x * 0.0625f);
    int y1 = (int)(rv.y * 0.0625f);
    int x2 = (int)(rv.z * 0.0625f);
    int y2 = (int)(rv.w * 0.0625f);
    int b = ridx[r];
    x1 = __builtin_amdgcn_readfirstlane(x1);
    y1 = __builtin_amdgcn_readfirstlane(y1);
    x2 = __builtin_amdgcn_readfirstlane(x2);
    y2 = __builtin_amdgcn_readfirstlane(y2);
    b = __builtin_amdgcn_readfirstlane(b);

    const int Lh = x2 - x1;
    const int Lw = y2 - y1;

    float* ob = out + ((size_t)(r * CC + s * CPS) + c) * (OUTP * OUTP) + ph * OUTP;

    const bool fast = (Lh >= 1 && Lh <= LMAX && Lw >= 1 && Lw <= LMAX &&
                       x1 >= 0 && y1 >= 0 && x2 < HH && y2 < WW);

    if (fast) {  // block-uniform branch
        const int h0 = x1 + (ph * Lh) / OUTP;
        const int nh = x1 + ((ph + 1) * Lh + OUTP - 1) / OUTP - h0;  // 1..4

        const float* base =
            featT + ((size_t)((s * BB + b) * HWSZ) + (size_t)h0 * WW + y1) * CPS + c;
        float* cm = colm + (ph * WSTG) * CPS + c;

        // Branch-specialized staging: straight-line, loads only real rows.
        if (nh == 1) stage_colmax<1>(base, Lw, cm);
        else if (nh == 2) stage_colmax<2>(base, Lw, cm);
        else if (nh == 3) stage_colmax<3>(base, Lw, cm);
        else stage_colmax<4>(base, Lw, cm);

        // Bins: each lane reads only its own colmax entries (no barrier).
#pragma unroll
        for (int pw = 0; pw < OUTP; ++pw) {
            const int w0 = (pw * Lw) / OUTP;
            const int nw = ((pw + 1) * Lw + OUTP - 1) / OUTP - w0;  // 1..4
            const float* q = cm + w0 * CPS;
            float m = q[0];
            if (nw > 1) m = fmaxf(m, q[CPS]);      // wave-uniform branches
            if (nw > 2) m = fmaxf(m, q[2 * CPS]);
            if (nw > 3) m = fmaxf(m, q[3 * CPS]);
            __builtin_nontemporal_store(m, ob + pw);
        }
    } else {
        // Generic fallback from featT (never taken for this distribution).
        int hs = x1 + (ph * Lh) / OUTP;
        int he = x1 + ((ph + 1) * Lh + OUTP - 1) / OUTP;
        hs = hs < 0 ? 0 : hs;
        he = he > HH ? HH : he;
        const float* fb = featT + (size_t)((s * BB + b) * HWSZ) * CPS + c;

#pragma unroll
        for (int pw = 0; pw < OUTP; ++pw) {
            int ws = y1 + (pw * Lw) / OUTP;
            int we = y1 + ((pw + 1) * Lw + OUTP - 1) / OUTP;
            ws = ws < 0 ? 0 : ws;
            we = we > WW ? WW : we;
            float m = NEGV;
            for (int h = hs; h < he; ++h) {
                for (int w = ws; w < we; ++w) {
                    m = fmaxf(m, fb[(size_t)(h * WW + w) * CPS]);
                }
            }
            ob[pw] = m;
        }
    }
}

extern "C" void kernel_launch(void* const* d_in, const int* in_sizes, int n_in,
                              void* d_out, int out_size, void* d_ws, size_t ws_size,
                              hipStream_t stream) {
    const float* features = (const float*)d_in[0];
    const float* rois = (const float*)d_in[1];
    const int* ridx = (const int*)d_in[2];
    float* out = (float*)d_out;
    const int R = in_sizes[1] / 4;

    const size_t tbytes = (size_t)BB * HWSZ * CC * sizeof(float);
    if (ws_size < tbytes) return;  // not expected (harness provides scratch)
    float* featT = (float*)d_ws;

    dim3 tg((HWSZ + 31) / 32, CC / 32, BB);
    transpose_k<<<tg, dim3(32, 8), 0, stream>>>(features, featT);
    roipool_cm<<<dim3(CSPLIT, R), 448, 0, stream>>>(featT, rois, ridx, out);
}

// Round 12
// 22.982 us; speedup vs baseline: 1.9443x; 1.9443x over previous
//
#include <hip/hip_runtime.h>
#include <cstddef>

// RoIPool: features (B=2, C=256, H=50, W=50) f32, rois (R,4) f32, roi_indices (R,) int
// out (R, C, 7, 7) f32.
// Reference quirk preserved: h-bins from x coords (ri[:,0], ri[:,2]), w-bins from y.
//
// R3-winning split structure + separable column-max:
//  kernel 1: transpose to (CSPLIT=4, B, H, W, 64) channel-last.
//  kernel 2: pool, grid (4, R), 448 thr = 7 waves (wave = ph, lane = channel).
//   - colmax[w] = max over the h-bin's <=4 rows (branch-specialized; loads
//     only real rows; ~Lw independent wave-coalesced load chains).
//   - each lane reads back ONLY ITS OWN colm entries (no sync needed) to
//     form 7 bin maxima in registers (dup-clamp <=4 LDS reads per bin).
//   - barrier -> st[] (union with colm) -> barrier -> R3's coalesced
//     nontemporal copy-out (448-lane contiguous stores). R11 post-mortem:
//     scattered per-lane 4B nt stores caused 4.4x HBM write amplification.
// LDS = 35840 B -> 4 blocks/CU = 28 waves/CU (R3-proven occupancy).

namespace {
constexpr int OUTP = 7;
constexpr int BB = 2;
constexpr int CC = 256;
constexpr int HH = 50;
constexpr int WW = 50;
constexpr int HWSZ = HH * WW;
constexpr int CSPLIT = 4;
constexpr int CPS = CC / CSPLIT;   // 64 channels per slice
constexpr int ROWS = WW * CPS;     // featT row stride in floats
constexpr int LMAX = 19;           // max Lh/Lw on fast path
constexpr int WSTG = 20;           // colmax slots per wave
constexpr float NEGV = -3e38f;
}  // namespace

// (B, C, H*W) -> (CSPLIT, B, H*W, CPS) tiled transpose via LDS (R3-proven).
__global__ __launch_bounds__(256) void transpose_k(const float* __restrict__ in,
                                                   float* __restrict__ out) {
    __shared__ float tile[32][33];
    const int b = blockIdx.z;
    const int hw0 = blockIdx.x * 32;
    const int c0 = blockIdx.y * 32;
    const int tx = threadIdx.x;
#pragma unroll
    for (int i = threadIdx.y; i < 32; i += 8) {
        const int hw = hw0 + tx;
        float v = 0.0f;
        if (hw < HWSZ) v = in[(size_t)(b * CC + c0 + i) * HWSZ + hw];
        tile[i][tx] = v;
    }
    __syncthreads();
    const int ch = c0 + tx;
    const int s = ch >> 6;
    const int cin = ch & (CPS - 1);
#pragma unroll
    for (int i = threadIdx.y; i < 32; i += 8) {
        const int hw = hw0 + i;
        if (hw < HWSZ)
            out[((size_t)((s * BB + b) * HWSZ) + hw) * CPS + cin] = tile[tx][i];
    }
}

// Stage colmax for NH rows: up to 20 independent load chains, scalar w<Lw branches.
template <int NH>
__device__ inline void stage_colmax(const float* __restrict__ base, int Lw,
                                    float* __restrict__ cm) {
#pragma unroll
    for (int w = 0; w < WSTG; ++w) {
        if (w < Lw) {  // wave-uniform scalar branch
            const float* p = base + w * CPS;
            float m = p[0];
            if (NH > 1) m = fmaxf(m, p[ROWS]);
            if (NH > 2) m = fmaxf(m, p[2 * ROWS]);
            if (NH > 3) m = fmaxf(m, p[3 * ROWS]);
            cm[w * CPS] = m;
        }
    }
}

// Pool: grid (CSPLIT, R), 448 thr; wave = ph, lane = channel.
__global__ __launch_bounds__(448) void roipool_cm(const float* __restrict__ featT,
                                                  const float* __restrict__ rois,
                                                  const int* __restrict__ ridx,
                                                  float* __restrict__ out) {
    __shared__ float lds[OUTP * WSTG * CPS];  // 8960 floats = 35840 B
    // phase 1: lds = colm[ph][w][c]; phase 2 (after barrier): lds[0..3135] = st

    const int s = blockIdx.x;
    const int r = blockIdx.y;
    const int tid = threadIdx.x;
    const int c = tid & 63;
    const int ph = __builtin_amdgcn_readfirstlane(tid >> 6);  // 0..6

    const float4 rv = reinterpret_cast<const float4*>(rois)[r];
    int x1 = (int)(rv.x * 0.0625f);
    int y1 = (int)(rv.y * 0.0625f);
    int x2 = (int)(rv.z * 0.0625f);
    int y2 = (int)(rv.w * 0.0625f);
    int b = ridx[r];
    x1 = __builtin_amdgcn_readfirstlane(x1);
    y1 = __builtin_amdgcn_readfirstlane(y1);
    x2 = __builtin_amdgcn_readfirstlane(x2);
    y2 = __builtin_amdgcn_readfirstlane(y2);
    b = __builtin_amdgcn_readfirstlane(b);

    const int Lh = x2 - x1;
    const int Lw = y2 - y1;

    float bm[OUTP];  // bin maxima (static-indexed registers)

    const bool fast = (Lh >= 1 && Lh <= LMAX && Lw >= 1 && Lw <= LMAX &&
                       x1 >= 0 && y1 >= 0 && x2 < HH && y2 < WW);

    if (fast) {  // block-uniform branch
        const int h0 = x1 + (ph * Lh) / OUTP;
        const int nh = x1 + ((ph + 1) * Lh + OUTP - 1) / OUTP - h0;  // 1..4

        const float* base =
            featT + ((size_t)((s * BB + b) * HWSZ) + (size_t)h0 * WW + y1) * CPS + c;
        float* cm = lds + (ph * WSTG) * CPS + c;

        // Branch-specialized staging: loads only real rows, full MLP.
        if (nh == 1) stage_colmax<1>(base, Lw, cm);
        else if (nh == 2) stage_colmax<2>(base, Lw, cm);
        else if (nh == 3) stage_colmax<3>(base, Lw, cm);
        else stage_colmax<4>(base, Lw, cm);

        // Each lane reads only its own colm entries (wave-private, no sync).
#pragma unroll
        for (int pw = 0; pw < OUTP; ++pw) {
            const int w0 = (pw * Lw) / OUTP;
            const int nw = ((pw + 1) * Lw + OUTP - 1) / OUTP - w0;  // 1..4
            const float* q = cm + w0 * CPS;
            float m = q[0];
            if (nw > 1) m = fmaxf(m, q[CPS]);      // wave-uniform branches
            if (nw > 2) m = fmaxf(m, q[2 * CPS]);
            if (nw > 3) m = fmaxf(m, q[3 * CPS]);
            bm[pw] = m;
        }
    } else {
        // Generic fallback from featT (never taken for this distribution).
        int hs = x1 + (ph * Lh) / OUTP;
        int he = x1 + ((ph + 1) * Lh + OUTP - 1) / OUTP;
        hs = hs < 0 ? 0 : hs;
        he = he > HH ? HH : he;
        const float* fb = featT + (size_t)((s * BB + b) * HWSZ) * CPS + c;

#pragma unroll
        for (int pw = 0; pw < OUTP; ++pw) {
            int ws = y1 + (pw * Lw) / OUTP;
            int we = y1 + ((pw + 1) * Lw + OUTP - 1) / OUTP;
            ws = ws < 0 ? 0 : ws;
            we = we > WW ? WW : we;
            float m = NEGV;
            for (int h = hs; h < he; ++h) {
                for (int w = ws; w < we; ++w) {
                    m = fmaxf(m, fb[(size_t)(h * WW + w) * CPS]);
                }
            }
            bm[pw] = m;
        }
    }

    // All waves done with colm before st overlays it.
    __syncthreads();
#pragma unroll
    for (int pw = 0; pw < OUTP; ++pw) lds[c * 49 + ph * OUTP + pw] = bm[pw];
    __syncthreads();

    // Coalesced nontemporal copy-out: 3136 floats = 448 threads x 7.
    float* ob = out + (size_t)(r * CC + s * CPS) * (OUTP * OUTP);
#pragma unroll
    for (int k = 0; k < OUTP; ++k) {
        __builtin_nontemporal_store(lds[tid + k * 448], ob + tid + k * 448);
    }
}

extern "C" void kernel_launch(void* const* d_in, const int* in_sizes, int n_in,
                              void* d_out, int out_size, void* d_ws, size_t ws_size,
                              hipStream_t stream) {
    const float* features = (const float*)d_in[0];
    const float* rois = (const float*)d_in[1];
    const int* ridx = (const int*)d_in[2];
    float* out = (float*)d_out;
    const int R = in_sizes[1] / 4;

    const size_t tbytes = (size_t)BB * HWSZ * CC * sizeof(float);
    if (ws_size < tbytes) return;  // not expected (harness provides scratch)
    float* featT = (float*)d_ws;

    dim3 tg((HWSZ + 31) / 32, CC / 32, BB);
    transpose_k<<<tg, dim3(32, 8), 0, stream>>>(features, featT);
    roipool_cm<<<dim3(CSPLIT, R), 448, 0, stream>>>(featT, rois, ridx, out);
}